// Round 7
// baseline (4359.748 us; speedup 1.0000x reference)
//
#include <hip/hip_runtime.h>
#include <math.h>

#define GN 32
#define AN 24
#define NN 768
#define EN 6144
#define TN 43008
#define MATD 169
#define EMBD 128
#define RBFD 16
#define SBFW 112
#define HEADS 16
#define CHD 256
#define LN 4
#define CUTF 5.0f
#define PIF 3.14159265358979323846f
#define INVS 0.25f         /* 1/sqrt(HD=16) */

__device__ __forceinline__ float siluf(float x){
  float s = 1.f/(1.f+expf(-x)); return x*s;
}
__device__ __forceinline__ float silugf(float x){
  float s = 1.f/(1.f+expf(-x)); return s*(1.f + x*(1.f-s));
}

// ---------------- 128x64-tile fp32 GEMM, 8x4 micro-tile, fused variants ----
// TRB: 0 C=A@B (B [K,Nc]); 1 C=A@B^T (B [Nc,K])
// SEL: 0 none; 1 nn with B chosen by output-col block of 256 (Nc=768);
//      2 nt-style with B chosen by k block of 256 (K=768), B [256,256];
//      3 nt-style block-diag: B[k,n] = Wsbf[(k>>8)][n][(k&255)]  (K=1024, Nc=112)
// AMOD (A-load): 0 none; 1 silu(A); 2 silu(cat(aux0,aux1)) K=256;
//      3 A*silugf(aux0); 4 silugf(A)*aux0[k]; 5 A*aux0[row];
//      6 concat-planes: A[k>>8-th plane of TN*CHD][row][k&255]  (K=1024)
// EPI: 0 (acc?C:0)+v+bias; 1 C=pre, out2=hin+silu(pre);
//      2 C=v*silugf(eaux0); 3 split cols: gp1/gp2 = v*silugf(p1/p2)
template<int TRB,int SEL,int AMOD,int EPI>
__global__ __launch_bounds__(256)
void gemmX(const float* __restrict__ A,
           const float* __restrict__ B0, const float* __restrict__ B1,
           const float* __restrict__ B2,
           const float* __restrict__ bias, float* __restrict__ C,
           float* __restrict__ out2,
           const float* __restrict__ aux0, const float* __restrict__ aux1,
           const float* __restrict__ eaux0, const float* __restrict__ eaux1,
           const float* __restrict__ hin,
           int M, int Nc, int K, int acc, size_t sA, size_t sB, size_t sC)
{
  const int z = blockIdx.z;
  A += (size_t)z*sA; C += (size_t)z*sC;
  const float* Bz = B0 + (size_t)z*sB;
  __shared__ __align__(16) float As[16][132];
  __shared__ __align__(16) float Bs[16][68];
  const int tid=threadIdx.x;
  const int br=blockIdx.y*128, bc=blockIdx.x*64;
  const int rm=(tid>>4)<<3, cn=(tid&15)<<2;
  float c32[8][4]={};
  for(int k0=0;k0<K;k0+=16){
    #pragma unroll
    for(int p=0;p<8;p++){
      int idx=p*256+tid; int r=idx>>4,c=idx&15;
      int gr=br+r, gc=k0+c;
      float v=0.f;
      if(gr<M&&gc<K){
        if(AMOD==0)      v=A[(size_t)gr*K+gc];
        else if(AMOD==1) v=siluf(A[(size_t)gr*K+gc]);
        else if(AMOD==2) v=siluf((gc<128?aux0:aux1)[(size_t)gr*128+(gc&127)]);
        else if(AMOD==3) v=A[(size_t)gr*K+gc]*silugf(aux0[(size_t)gr*K+gc]);
        else if(AMOD==4) v=silugf(A[(size_t)gr*K+gc])*aux0[gc];
        else if(AMOD==5) v=A[(size_t)gr*K+gc]*aux0[gr];
        else             v=A[(size_t)(gc>>8)*((size_t)TN*CHD)+(size_t)gr*CHD+(gc&255)];
      }
      As[c][r]=v;
    }
    #pragma unroll
    for(int p=0;p<4;p++){
      int idx=p*256+tid;
      float v=0.f;
      if(SEL==1){
        int kk=idx>>6, n=idx&63;
        int gk=k0+kk, gn=bc+n;
        const float* Bp=(bc<256)?B0:(bc<512)?B1:B2;
        if(gk<K&&gn<Nc) v=Bp[(size_t)gk*256+(gn&255)];
        Bs[kk][n]=v;
      } else if(SEL==2){
        int n=idx>>4, c=idx&15;
        int gn=bc+n, gk=k0+c;
        const float* Bp=(k0<256)?B0:(k0<512)?B1:B2;
        if(gn<Nc&&gk<K) v=Bp[(size_t)gn*256+(gk&255)];
        Bs[c][n]=v;
      } else if(SEL==3){
        int n=idx>>4, c=idx&15;
        int gn=bc+n, gk=k0+c;
        if(gn<Nc&&gk<K) v=B0[(size_t)(gk>>8)*(SBFW*CHD)+(size_t)gn*CHD+(gk&255)];
        Bs[c][n]=v;
      } else if(TRB==0){
        int kk=idx>>6, n=idx&63;
        int gk=k0+kk, gn=bc+n;
        if(gk<K&&gn<Nc) v=Bz[(size_t)gk*Nc+gn];
        Bs[kk][n]=v;
      } else {
        int n=idx>>4, c=idx&15;
        int gn=bc+n, gk=k0+c;
        if(gn<Nc&&gk<K) v=Bz[(size_t)gn*K+gk];
        Bs[c][n]=v;
      }
    }
    __syncthreads();
    #pragma unroll
    for(int kk=0;kk<16;kk++){
      float4 a0=*reinterpret_cast<const float4*>(&As[kk][rm]);
      float4 a1=*reinterpret_cast<const float4*>(&As[kk][rm+4]);
      float4 bv=*reinterpret_cast<const float4*>(&Bs[kk][cn]);
      float a8[8]={a0.x,a0.y,a0.z,a0.w,a1.x,a1.y,a1.z,a1.w};
      float b4[4]={bv.x,bv.y,bv.z,bv.w};
      #pragma unroll
      for(int i=0;i<8;i++)
        #pragma unroll
        for(int j=0;j<4;j++) c32[i][j]+=a8[i]*b4[j];
    }
    __syncthreads();
  }
  #pragma unroll
  for(int i=0;i<8;i++){
    int r=br+rm+i; if(r>=M) continue;
    #pragma unroll
    for(int j=0;j<4;j++){
      int col=bc+cn+j; if(col>=Nc) continue;
      size_t o=(size_t)r*Nc+col;
      float v=c32[i][j];
      if(EPI==0){
        float bb=bias?bias[col]:0.f;
        C[o]=(acc?C[o]:0.f)+v+bb;
      } else if(EPI==1){
        float pre=v+(bias?bias[col]:0.f);
        C[o]=pre;
        out2[o]=hin[o]+siluf(pre);
      } else if(EPI==2){
        C[o]=v*silugf(eaux0[o]);
      } else {
        size_t oo=(size_t)r*128+(col&127);
        if(col<128) C[oo]=v*silugf(eaux0[oo]);
        else        out2[oo]=v*silugf(eaux1[oo]);
      }
    }
  }
}

// ---------------- init ----------------
__global__ void k_init(float* __restrict__ out, float* __restrict__ gpos)
{
  int i=blockIdx.x*256+threadIdx.x;
  if(i<GN) out[i]=0.f;
  if(i<NN*3) gpos[i]=0.f;
}

// ---------------- forward geometry / elementwise ----------------
__global__ void k_edge_geom(const float* __restrict__ pos, const int* __restrict__ ei,
                            float* __restrict__ dv, float* __restrict__ env,
                            float* __restrict__ denv, float* __restrict__ nrbf)
{
  int e = blockIdx.x*256+threadIdx.x; if(e>=EN) return;
  int s = ei[e], t = ei[EN+e];
  float dx=pos[3*s]-pos[3*t], dy=pos[3*s+1]-pos[3*t+1], dz=pos[3*s+2]-pos[3*t+2];
  float d = sqrtf(dx*dx+dy*dy+dz*dz);
  float u = d/CUTF, ev=0.f, dev=0.f;
  if (u<1.f){
    float u2=u*u, u4=u2*u2, u5=u4*u;
    ev  = 1.f - 21.f*u5 + 35.f*u5*u - 15.f*u5*u2;
    dev = (-105.f*u4 + 210.f*u5 - 105.f*u4*u2)/CUTF;
  }
  dv[e]=d; env[e]=ev; denv[e]=dev;
  const float C0 = sqrtf(2.f/CUTF);
  #pragma unroll
  for (int n=0;n<RBFD;n++){
    float wv = (n+1)*PIF/CUTF;
    nrbf[e*RBFD+n] = C0*sinf(wv*d)/d*ev;
  }
}

__global__ void k_ang(const float* __restrict__ pos, const int* __restrict__ ai,
                      const int* __restrict__ aj, const int* __restrict__ ak,
                      float* __restrict__ ang)
{
  int t = blockIdx.x*256+threadIdx.x; if(t>=TN) return;
  int i=ai[t], j=aj[t], k=ak[t];
  float jix=pos[3*i]-pos[3*j], jiy=pos[3*i+1]-pos[3*j+1], jiz=pos[3*i+2]-pos[3*j+2];
  float jkx=pos[3*k]-pos[3*j], jky=pos[3*k+1]-pos[3*j+1], jkz=pos[3*k+2]-pos[3*j+2];
  float cx=jiy*jkz-jiz*jky, cy=jiz*jkx-jix*jkz, cz=jix*jky-jiy*jkx;
  float cn=sqrtf(cx*cx+cy*cy+cz*cz);
  float dt=jix*jkx+jiy*jky+jiz*jkz;
  ang[t]=atan2f(cn,dt);
}

__global__ void k_sbf(const float* __restrict__ ang, const float* __restrict__ nrbf,
                      const int* __restrict__ neo0, float* __restrict__ sbf)
{
  int i = blockIdx.x*256+threadIdx.x; if(i>=TN*SBFW) return;
  int t = i/SBFW, col = i - t*SBFW;
  int l = col>>4, n = col&15;
  int e2 = neo0[t];
  sbf[i] = cosf((float)l*ang[t])*nrbf[e2*RBFD+n];
}

__global__ void k_embx(const int* __restrict__ x, const float* __restrict__ tab,
                       float* __restrict__ embx)
{
  int i = blockIdx.x*256+threadIdx.x; if(i>=NN*EMBD) return;
  int n=i>>7, c=i&127;
  embx[i]=tab[x[n]*EMBD+c];
}

// ---------------- attention (per dst-edge x head; 7 contiguous triplets) ---
// qkv packed [E, 768] = q|k|v
__global__ void k_attn_fwd(const float* __restrict__ qkv, const float* __restrict__ esb,
                           const float* __restrict__ eatn, const int* __restrict__ neo0,
                           float* __restrict__ attn, float* __restrict__ agg)
{
  int idx = blockIdx.x*256+threadIdx.x;
  if (idx>=EN*HEADS) return;
  int e = idx/HEADS, h = idx%HEADS;
  int n = e>>3;
  float qv[16], evv[16];
  #pragma unroll
  for (int d=0;d<16;d++){
    qv[d]=qkv[(size_t)e*768+h*16+d];
    evv[d]=eatn[(size_t)n*CHD+h*16+d];
  }
  float lg[7]; int src[7];
  for (int jj=0;jj<7;jj++){
    int t=e*7+jj; int sE=neo0[t]; src[jj]=sE;
    const float* ep = esb + (size_t)t*CHD + h*16;
    const float* kp = qkv + (size_t)sE*768 + 256 + h*16;
    float s=0.f;
    #pragma unroll
    for (int d=0;d<16;d++) s += qv[d]*(kp[d]*ep[d]+evv[d]);
    lg[jj]=s*INVS;
  }
  float m=lg[0];
  for(int jj=1;jj<7;jj++) m=fmaxf(m,lg[jj]);
  float ex[7], den=0.f;
  for(int jj=0;jj<7;jj++){ ex[jj]=expf(lg[jj]-m); den+=ex[jj]; }
  float rd=1.f/(den+1e-16f);
  float av[16];
  #pragma unroll
  for(int d=0;d<16;d++) av[d]=0.f;
  for(int jj=0;jj<7;jj++){
    int t=e*7+jj;
    float at=ex[jj]*rd;
    attn[(size_t)t*HEADS+h]=at;
    const float* ep = esb + (size_t)t*CHD + h*16;
    const float* vp = qkv + (size_t)src[jj]*768 + 512 + h*16;
    #pragma unroll
    for(int d=0;d<16;d++) av[d]+=at*vp[d]*ep[d];
  }
  #pragma unroll
  for(int d=0;d<16;d++) agg[(size_t)e*CHD+h*16+d]=av[d];
}

__global__ void k_edge_out(const float* __restrict__ g1pre, const float* __restrict__ w2,
                           const float* __restrict__ b2, const int* __restrict__ eb,
                           float* __restrict__ ob)
{
  int e=blockIdx.x*256+threadIdx.x; if(e>=EN) return;
  float s=b2[0];
  for(int c=0;c<EMBD;c++) s += siluf(g1pre[e*EMBD+c])*w2[c];
  atomicAdd(&ob[eb[e]], s);
}

// ---------------- backward attention ----------------
__global__ void k_attn_bwd_edge(const float* __restrict__ qkv, const float* __restrict__ esb,
                                const float* __restrict__ eatn, const float* __restrict__ attn,
                                const float* __restrict__ gagg, const int* __restrict__ neo0,
                                float* __restrict__ gqkv, float* __restrict__ gesb,
                                float* __restrict__ glog)
{
  int idx=blockIdx.x*256+threadIdx.x;
  if(idx>=EN*HEADS) return;
  int e=idx/HEADS, h=idx%HEADS;
  int n=e>>3;
  float qv[16], evv[16], gv[16];
  #pragma unroll
  for(int d=0;d<16;d++){
    qv[d]=qkv[(size_t)e*768+h*16+d];
    evv[d]=eatn[(size_t)n*CHD+h*16+d];
    gv[d]=gagg[(size_t)e*CHD+h*16+d];
  }
  float ga[7], at[7]; int src[7];
  for(int jj=0;jj<7;jj++){
    int t=e*7+jj; int sE=neo0[t]; src[jj]=sE;
    at[jj]=attn[(size_t)t*HEADS+h];
    const float* ep=esb+(size_t)t*CHD+h*16;
    const float* vp=qkv+(size_t)sE*768+512+h*16;
    float s=0.f;
    #pragma unroll
    for(int d=0;d<16;d++) s+=gv[d]*vp[d]*ep[d];
    ga[jj]=s;
  }
  float sm=0.f;
  for(int jj=0;jj<7;jj++) sm+=at[jj]*ga[jj];
  float gqv[16];
  #pragma unroll
  for(int d=0;d<16;d++) gqv[d]=0.f;
  for(int jj=0;jj<7;jj++){
    int t=e*7+jj; int sE=src[jj];
    float gl=at[jj]*(ga[jj]-sm);
    glog[(size_t)t*HEADS+h]=gl;
    const float* ep=esb+(size_t)t*CHD+h*16;
    const float* kp=qkv+(size_t)sE*768+256+h*16;
    const float* vp=qkv+(size_t)sE*768+512+h*16;
    float* gp=gesb+(size_t)t*CHD+h*16;
    #pragma unroll
    for(int d=0;d<16;d++){
      float es=ep[d], kk=kp[d];
      gqv[d]+=gl*INVS*(kk*es+evv[d]);
      gp[d]=at[jj]*vp[d]*gv[d]+gl*INVS*qv[d]*kk;
    }
  }
  #pragma unroll
  for(int d=0;d<16;d++) gqkv[(size_t)e*768+h*16+d]=gqv[d];
}

// per src edge: its 7 triplets are t = n*56 + a*7 + (b - (b>a)), a != b
__global__ void k_attn_bwd_src(const float* __restrict__ qkv, const float* __restrict__ esb,
                               const float* __restrict__ attn, const float* __restrict__ gagg,
                               const float* __restrict__ glog, float* __restrict__ gqkv)
{
  int idx=blockIdx.x*256+threadIdx.x;
  if(idx>=EN*HEADS) return;
  int e=idx/HEADS, h=idx%HEADS;   // e = src edge
  int n=e>>3, b=e&7;
  float gkk[16], gvv[16];
  #pragma unroll
  for(int d=0;d<16;d++){ gkk[d]=0.f; gvv[d]=0.f; }
  for(int a=0;a<8;a++){
    if(a==b) continue;
    int t = n*56 + a*7 + (b>a ? b-1 : b);
    int de = n*8 + a;
    float gl=glog[(size_t)t*HEADS+h]*INVS;
    float at=attn[(size_t)t*HEADS+h];
    const float* ep=esb+(size_t)t*CHD+h*16;
    const float* qp=qkv+(size_t)de*768+h*16;
    const float* gp=gagg+(size_t)de*CHD+h*16;
    #pragma unroll
    for(int d=0;d<16;d++){
      float es=ep[d];
      gkk[d]+=gl*qp[d]*es;
      gvv[d]+=at*es*gp[d];
    }
  }
  #pragma unroll
  for(int d=0;d<16;d++){
    gqkv[(size_t)e*768+256+h*16+d]=gkk[d];
    gqkv[(size_t)e*768+512+h*16+d]=gvv[d];
  }
}

// ---------------- backward tail ----------------
__global__ void k_edge_bwd(const float* __restrict__ geaenv, const float* __restrict__ ea,
                           const float* __restrict__ env, const float* __restrict__ denv,
                           const float* __restrict__ dv, const float* __restrict__ gnr,
                           float* __restrict__ eag, float* __restrict__ gd)
{
  int e=blockIdx.x*256+threadIdx.x; if(e>=EN) return;
  float ev=env[e], dev=denv[e], d=dv[e];
  float gmat=0.f;
  for(int m=0;m<MATD;m++){
    float g=geaenv[e*MATD+m];
    eag[e*MATD+m]=g*ev;
    gmat+=g*ea[e*MATD+m];
  }
  float acc=gmat*dev;
  const float C0=sqrtf(2.f/CUTF);
  for(int n=0;n<RBFD;n++){
    float wv=(n+1)*PIF/CUTF;
    float sn,cs; sincosf(wv*d,&sn,&cs);
    float rb=C0*sn/d;
    float rbp=C0*(wv*cs/d - sn/(d*d));
    acc += gnr[e*RBFD+n]*(rbp*ev+rb*dev);
  }
  gd[e]=acc;
}

__global__ void k_sbf_bwd(const float* __restrict__ gsbf, const float* __restrict__ ang,
                          const float* __restrict__ dv, const float* __restrict__ env,
                          const float* __restrict__ denv, const float* __restrict__ nrbf,
                          const int* __restrict__ neo0, const int* __restrict__ ai,
                          const int* __restrict__ aj, const int* __restrict__ ak,
                          const float* __restrict__ pos,
                          float* __restrict__ gd, float* __restrict__ gpos)
{
  int t=blockIdx.x*256+threadIdx.x; if(t>=TN) return;
  int e2=neo0[t];
  float a=ang[t];
  float rad[16], gr[16];
  #pragma unroll
  for(int n=0;n<16;n++){ rad[n]=nrbf[e2*RBFD+n]; gr[n]=0.f; }
  float gang=0.f;
  for(int l=0;l<7;l++){
    float sl,cl; sincosf((float)l*a,&sl,&cl);
    float srow=0.f;
    #pragma unroll
    for(int n=0;n<16;n++){
      float gs=gsbf[(size_t)t*SBFW+l*16+n];
      gr[n]+=gs*cl;
      srow+=gs*rad[n];
    }
    gang+=-(float)l*sl*srow;
  }
  float d2=dv[e2], ev=env[e2], dev=denv[e2];
  const float C0=sqrtf(2.f/CUTF);
  float gdd=0.f;
  for(int n=0;n<16;n++){
    float wv=(n+1)*PIF/CUTF;
    float sn,cs; sincosf(wv*d2,&sn,&cs);
    float rb=C0*sn/d2;
    float rbp=C0*(wv*cs/d2 - sn/(d2*d2));
    gdd+=gr[n]*(rbp*ev+rb*dev);
  }
  atomicAdd(&gd[e2],gdd);
  int i=ai[t], j=aj[t], k=ak[t];
  float jix=pos[3*i]-pos[3*j], jiy=pos[3*i+1]-pos[3*j+1], jiz=pos[3*i+2]-pos[3*j+2];
  float jkx=pos[3*k]-pos[3*j], jky=pos[3*k+1]-pos[3*j+1], jkz=pos[3*k+2]-pos[3*j+2];
  float cx=jiy*jkz-jiz*jky, cy=jiz*jkx-jix*jkz, cz=jix*jky-jiy*jkx;
  float cn2=cx*cx+cy*cy+cz*cz;
  float cn=sqrtf(cn2);
  float dt=jix*jkx+jiy*jky+jiz*jkz;
  float den=cn2+dt*dt;
  float coef=gang/den;
  float rc=dt/cn;
  float axv=jky*cz-jkz*cy, ayv=jkz*cx-jkx*cz, azv=jkx*cy-jky*cx;  // jk x c
  float bxv=cy*jiz-cz*jiy, byv=cz*jix-cx*jiz, bzv=cx*jiy-cy*jix;  // c x ji
  float gjix=coef*(rc*axv-cn*jkx), gjiy=coef*(rc*ayv-cn*jky), gjiz=coef*(rc*azv-cn*jkz);
  float gjkx=coef*(rc*bxv-cn*jix), gjky=coef*(rc*byv-cn*jiy), gjkz=coef*(rc*bzv-cn*jiz);
  atomicAdd(&gpos[3*i],gjix); atomicAdd(&gpos[3*i+1],gjiy); atomicAdd(&gpos[3*i+2],gjiz);
  atomicAdd(&gpos[3*k],gjkx); atomicAdd(&gpos[3*k+1],gjky); atomicAdd(&gpos[3*k+2],gjkz);
  atomicAdd(&gpos[3*j],-(gjix+gjkx)); atomicAdd(&gpos[3*j+1],-(gjiy+gjky)); atomicAdd(&gpos[3*j+2],-(gjiz+gjkz));
}

__global__ void k_d_bwd(const float* __restrict__ gd, const float* __restrict__ dv,
                        const float* __restrict__ pos, const int* __restrict__ ei,
                        float* __restrict__ gpos)
{
  int e=blockIdx.x*256+threadIdx.x; if(e>=EN) return;
  int s=ei[e], t=ei[EN+e];
  float g=gd[e]/dv[e];
  float dx=pos[3*s]-pos[3*t], dy=pos[3*s+1]-pos[3*t+1], dz=pos[3*s+2]-pos[3*t+2];
  atomicAdd(&gpos[3*s], g*dx); atomicAdd(&gpos[3*s+1], g*dy); atomicAdd(&gpos[3*s+2], g*dz);
  atomicAdd(&gpos[3*t], -g*dx); atomicAdd(&gpos[3*t+1], -g*dy); atomicAdd(&gpos[3*t+2], -g*dz);
}

// contrib[e,a,c] = sum_m G[e,a,c,m]*eag[e,m], summed over 192 edges/graph.
__global__ __launch_bounds__(256)
void k_einsum2(const float* __restrict__ G_, const float* __restrict__ eag,
               float* __restrict__ gpos)
{
  __shared__ float eL[48*MATD];
  int bid = blockIdx.x;                   // 32*18*4 = 2304
  int g = bid/72, rem = bid%72;
  int acg = rem>>2, ech = rem&3;
  int e0 = g*192 + ech*48;
  for (int i=threadIdx.x; i<48*MATD; i+=256)
    eL[i] = eag[(size_t)e0*MATD + i];
  __syncthreads();
  int wv = threadIdx.x>>6, lane = threadIdx.x&63;
  int ac = acg*4 + wv;
  float s=0.f;
  for (int e=0;e<48;e++){
    const float* Gp = G_ + ((size_t)(e0+e)*(AN*3) + ac)*MATD;
    const float* Ep = eL + e*MATD;
    s += Gp[lane]*Ep[lane];
    s += Gp[lane+64]*Ep[lane+64];
    if (lane<41) s += Gp[lane+128]*Ep[lane+128];
  }
  #pragma unroll
  for (int o=32;o>0;o>>=1) s += __shfl_down(s,o,64);
  if (lane==0) atomicAdd(&gpos[g*(AN*3)+ac], s);
}

__global__ void k_force(const float* __restrict__ gpos, float* __restrict__ ob)
{
  int i=blockIdx.x*256+threadIdx.x; if(i>=NN*3) return;
  ob[GN+i]=-gpos[i];
}

extern "C" void kernel_launch(void* const* d_in, const int* in_sizes, int n_in,
                              void* d_out, int out_size, void* d_ws, size_t ws_size,
                              hipStream_t stream)
{
  const int*   x      = (const int*)d_in[0];
  const int*   ei     = (const int*)d_in[1];
  const int*   neo    = (const int*)d_in[2];
  const int*   ai     = (const int*)d_in[3];
  const int*   aj     = (const int*)d_in[4];
  const int*   ak     = (const int*)d_in[5];
  const int*   eb     = (const int*)d_in[6];
  const float* pos    = (const float*)d_in[8];
  const float* eattr  = (const float*)d_in[9];
  const float* eagrad = (const float*)d_in[10];
  const float* etab   = (const float*)d_in[11];
  const float* matW   = (const float*)d_in[12];
  const float* matB   = (const float*)d_in[13];
  const float* rbfW   = (const float*)d_in[14];
  const float* rbfB   = (const float*)d_in[15];
  const float* embtW  = (const float*)d_in[16];
  const float* embtB  = (const float*)d_in[17];
  const float* inW    = (const float*)d_in[18];
  const float* inB    = (const float*)d_in[19];
  const float* Wq     = (const float*)d_in[20];
  const float* Wk     = (const float*)d_in[21];
  const float* Wv     = (const float*)d_in[22];
  const float* Wo     = (const float*)d_in[23];
  const float* bo     = (const float*)d_in[24];
  const float* Wsbf   = (const float*)d_in[25];
  const float* Weat   = (const float*)d_in[26];
  const float* o1W    = (const float*)d_in[27];
  const float* o1B    = (const float*)d_in[28];
  const float* o2W    = (const float*)d_in[29];
  const float* o2B    = (const float*)d_in[30];
  float* out = (float*)d_out;
  (void)in_sizes; (void)n_in; (void)out_size; (void)ws_size;

  float* w=(float*)d_ws;
  size_t off=0;
  auto A=[&](size_t n){ float* p=w+off; off+=n; return p; };
  float* dv    = A(EN);
  float* env   = A(EN);
  float* denv  = A(EN);
  float* gd    = A(EN);
  float* nrbf  = A((size_t)EN*RBFD);
  float* gnr   = A((size_t)EN*RBFD);
  float* geaenv= A((size_t)EN*MATD);
  float* eag   = A((size_t)EN*MATD);
  float* p1    = A((size_t)EN*EMBD);
  float* p2    = A((size_t)EN*EMBD);
  float* p3    = A((size_t)EN*EMBD);
  float* g1pre = A((size_t)EN*EMBD);
  float* ghpre = A((size_t)EN*EMBD);
  float* gp1   = A((size_t)EN*EMBD);
  float* gp2   = A((size_t)EN*EMBD);
  float* hlay  = A((size_t)5*EN*CHD);
  float* qkv4  = A((size_t)4*EN*768);
  float* gqkv  = A((size_t)EN*768);
  float* eatn4 = A((size_t)4*NN*CHD);
  float* sc2   = A((size_t)EN*CHD);     // agg fwd / grad_agg bwd
  float* gradh = A((size_t)EN*CHD);
  float* opre4 = A((size_t)4*EN*CHD);
  float* sbf   = A((size_t)TN*SBFW);
  float* gsbf  = A((size_t)TN*SBFW);
  float* angb  = A(TN);
  float* attn4 = A((size_t)4*TN*HEADS);
  float* glog  = A((size_t)TN*HEADS);
  float* esb4  = A((size_t)4*TN*CHD);   // per-layer, stored fwd->bwd
  float* gesb4 = A((size_t)4*TN*CHD);   // per-layer, consumed by one K=1024 GEMM
  float* embx  = A((size_t)NN*EMBD);
  float* gpos  = A((size_t)NN*3);
  // total ~151M floats ~= 604 MB

  #define GX(TRB,SEL,AMOD,EPI, Ap,B0p,B1p,B2p,biasp,Cp,o2p,a0p,a1p,e0p,e1p,hinp, M,Nc,K,acc,sA,sB,sC,batch) \
    hipLaunchKernelGGL((gemmX<TRB,SEL,AMOD,EPI>), dim3(((Nc)+63)/64,((M)+127)/128,(batch)), dim3(256),0,stream, \
      Ap,B0p,B1p,B2p,biasp,Cp,o2p,a0p,a1p,e0p,e1p,hinp, M,Nc,K,acc,(size_t)(sA),(size_t)(sB),(size_t)(sC))

  const float* FN = nullptr; float* FNm = nullptr;

  // ---------- init + geometry ----------
  hipLaunchKernelGGL(k_init, dim3((NN*3+255)/256),dim3(256),0,stream, out,gpos);
  hipLaunchKernelGGL(k_edge_geom, dim3((EN+255)/256),dim3(256),0,stream, pos,ei,dv,env,denv,nrbf);
  hipLaunchKernelGGL(k_ang, dim3((TN+255)/256),dim3(256),0,stream, pos,ai,aj,ak,angb);
  hipLaunchKernelGGL(k_sbf, dim3((TN*SBFW+255)/256),dim3(256),0,stream, angb,nrbf,neo,sbf);
  hipLaunchKernelGGL(k_embx, dim3((NN*EMBD+255)/256),dim3(256),0,stream, x,etab,embx);

  // ---------- embedding MLP ----------
  GX(0,0,5,0, eattr,matW,FN,FN, matB, p1, FNm, env,FN, FN,FN,FN, EN,EMBD,MATD,0, 0,0,0, 1);
  GX(0,0,0,0, nrbf, rbfW,FN,FN, rbfB, p2, FNm, FN,FN, FN,FN,FN, EN,EMBD,RBFD,0, 0,0,0, 1);
  GX(0,0,2,0, p1, embtW,FN,FN, embtB, p3, FNm, p1,p2, FN,FN,FN, EN,EMBD,CHD,0, 0,0,0, 1);
  GX(0,0,1,0, p3, inW,FN,FN, inB, hlay, FNm, FN,FN, FN,FN,FN, EN,CHD,EMBD,0, 0,0,0, 1);

  // ---------- batched per-layer precompute ----------
  GX(0,0,0,0, embx, Weat,FN,FN, FN, eatn4, FNm, FN,FN, FN,FN,FN,
     NN,CHD,EMBD,0, 0,(size_t)EMBD*CHD,(size_t)NN*CHD, LN);
  GX(0,0,0,0, sbf, Wsbf,FN,FN, FN, esb4, FNm, FN,FN, FN,FN,FN,
     TN,CHD,SBFW,0, 0,(size_t)SBFW*CHD,(size_t)TN*CHD, LN);

  // ---------- forward layers ----------
  for (int l=0;l<LN;l++){
    float* hl   = hlay+(size_t)l*EN*CHD;
    float* qkvl = qkv4+(size_t)l*EN*768;
    float* esbl = esb4+(size_t)l*TN*CHD;
    float* eatl = eatn4+(size_t)l*NN*CHD;
    float* attl = attn4+(size_t)l*TN*HEADS;
    float* opl  = opre4+(size_t)l*EN*CHD;
    GX(0,1,0,0, hl, Wq+(size_t)l*CHD*CHD, Wk+(size_t)l*CHD*CHD, Wv+(size_t)l*CHD*CHD,
       FN, qkvl, FNm, FN,FN, FN,FN,FN, EN,768,CHD,0, 0,0,0, 1);
    hipLaunchKernelGGL(k_attn_fwd, dim3((EN*HEADS+255)/256),dim3(256),0,stream,
                       qkvl,esbl,eatl,neo,attl,sc2);
    GX(0,0,0,1, sc2, Wo+(size_t)l*CHD*CHD,FN,FN, bo+(size_t)l*CHD, opl,
       hlay+(size_t)(l+1)*EN*CHD, FN,FN, FN,FN, hl, EN,CHD,CHD,0, 0,0,0, 1);
  }
  const float* h4=hlay+(size_t)4*EN*CHD;
  GX(0,0,0,0, h4, o1W,FN,FN, o1B, g1pre, FNm, FN,FN, FN,FN,FN, EN,EMBD,CHD,0, 0,0,0, 1);
  hipLaunchKernelGGL(k_edge_out, dim3((EN+255)/256),dim3(256),0,stream, g1pre,o2W,o2B,eb,out);

  // ---------- backward ----------
  GX(1,0,4,0, g1pre, o1W,FN,FN, FN, gradh, FNm, o2W,FN, FN,FN,FN, EN,CHD,EMBD,0, 0,0,0, 1);

  for (int l=LN-1;l>=0;l--){
    float* qkvl = qkv4+(size_t)l*EN*768;
    float* esbl = esb4+(size_t)l*TN*CHD;
    float* eatl = eatn4+(size_t)l*NN*CHD;
    float* attl = attn4+(size_t)l*TN*HEADS;
    float* opl  = opre4+(size_t)l*EN*CHD;
    float* gesbl= gesb4+(size_t)l*TN*CHD;
    GX(1,0,3,0, gradh, Wo+(size_t)l*CHD*CHD,FN,FN, FN, sc2, FNm, opl,FN, FN,FN,FN,
       EN,CHD,CHD,0, 0,0,0, 1);   // grad_agg
    hipLaunchKernelGGL(k_attn_bwd_edge, dim3((EN*HEADS+255)/256),dim3(256),0,stream,
                       qkvl,esbl,eatl,attl,sc2,neo,gqkv,gesbl,glog);
    hipLaunchKernelGGL(k_attn_bwd_src, dim3((EN*HEADS+255)/256),dim3(256),0,stream,
                       qkvl,esbl,attl,sc2,glog,gqkv);
    GX(0,2,0,0, gqkv, Wq+(size_t)l*CHD*CHD, Wk+(size_t)l*CHD*CHD, Wv+(size_t)l*CHD*CHD,
       FN, gradh, FNm, FN,FN, FN,FN,FN, EN,CHD,768,1, 0,0,0, 1);
  }

  // gsbf = sum_l gesb_l @ Wsbf_l^T  -- one K=1024 block-diagonal GEMM
  GX(1,3,6,0, gesb4, Wsbf,FN,FN, FN, gsbf, FNm, FN,FN, FN,FN,FN,
     TN,SBFW,1024,0, 0,0,0, 1);

  GX(1,0,0,2, gradh, inW,FN,FN, FN, ghpre, FNm, FN,FN, p3,FN,FN, EN,EMBD,CHD,0, 0,0,0, 1);
  GX(1,0,0,3, ghpre, embtW,FN,FN, FN, gp1, gp2, FN,FN, p1,p2,FN, EN,CHD,EMBD,0, 0,0,0, 1);
  GX(1,0,0,0, gp2, rbfW,FN,FN, FN, gnr, FNm, FN,FN, FN,FN,FN, EN,RBFD,EMBD,0, 0,0,0, 1);
  GX(1,0,0,0, gp1, matW,FN,FN, FN, geaenv, FNm, FN,FN, FN,FN,FN, EN,MATD,EMBD,0, 0,0,0, 1);
  hipLaunchKernelGGL(k_edge_bwd, dim3((EN+255)/256),dim3(256),0,stream,
                     geaenv,eattr,env,denv,dv,gnr,eag,gd);
  hipLaunchKernelGGL(k_sbf_bwd, dim3((TN+255)/256),dim3(256),0,stream,
                     gsbf,angb,dv,env,denv,nrbf,neo,ai,aj,ak,pos,gd,gpos);
  hipLaunchKernelGGL(k_d_bwd, dim3((EN+255)/256),dim3(256),0,stream, gd,dv,pos,ei,gpos);
  hipLaunchKernelGGL(k_einsum2, dim3(2304),dim3(256),0,stream, eagrad,eag,gpos);
  hipLaunchKernelGGL(k_force, dim3((NN*3+255)/256),dim3(256),0,stream, gpos,out);
  #undef GX
}

// Round 9
// 3302.237 us; speedup vs baseline: 1.3202x; 1.3202x over previous
//
#include <hip/hip_runtime.h>
#include <math.h>

#define GN 32
#define AN 24
#define NN 768
#define EN 6144
#define TN 43008
#define MATD 169
#define EMBD 128
#define RBFD 16
#define SBFW 112
#define HEADS 16
#define CHD 256
#define LN 4
#define CUTF 5.0f
#define PIF 3.14159265358979323846f
#define INVS 0.25f         /* 1/sqrt(HD=16) */

__device__ __forceinline__ float siluf(float x){
  float s = 1.f/(1.f+expf(-x)); return x*s;
}
__device__ __forceinline__ float silugf(float x){
  float s = 1.f/(1.f+expf(-x)); return s*(1.f + x*(1.f-s));
}
__device__ __forceinline__ float4 m4(float4 a,float4 b){ return make_float4(a.x*b.x,a.y*b.y,a.z*b.z,a.w*b.w); }
__device__ __forceinline__ float4 a4(float4 a,float4 b){ return make_float4(a.x+b.x,a.y+b.y,a.z+b.z,a.w+b.w); }
__device__ __forceinline__ float4 s4(float4 a,float s){ return make_float4(a.x*s,a.y*s,a.z*s,a.w*s); }
__device__ __forceinline__ float  d4(float4 a,float4 b){ return a.x*b.x+a.y*b.y+a.z*b.z+a.w*b.w; }
__device__ __forceinline__ float4 fma4(float4 c,float s,float4 v){
  c.x+=s*v.x; c.y+=s*v.y; c.z+=s*v.z; c.w+=s*v.w; return c; }

// ---------------- 64x64-tile fp32 GEMM, 4x4 micro-tile, fused variants ----
// (round-4 proven version)
// TRB: 0 C=A@B (B [K,Nc]); 1 C=A@B^T (B [Nc,K])
// SEL: 0 none; 1 nn with B chosen by output-col block of 256 (Nc=768);
//      2 nt-style with B chosen by k block of 256 (K=768), B [256,256]
// AMOD: 0 none; 1 silu(A); 2 silu(cat(aux0,aux1)) K=256;
//      3 A*silugf(aux0); 4 silugf(A)*aux0[k]; 5 A*aux0[row]
// EPI: 0 (acc?C:0)+v+bias; 1 C=pre, out2=hin+silu(pre);
//      2 C=v*silugf(eaux0); 3 split cols: gp1/gp2 = v*silugf(p1/p2)
template<int TRB,int SEL,int AMOD,int EPI>
__global__ __launch_bounds__(256)
void gemmX(const float* __restrict__ A,
           const float* __restrict__ B0, const float* __restrict__ B1,
           const float* __restrict__ B2,
           const float* __restrict__ bias, float* __restrict__ C,
           float* __restrict__ out2,
           const float* __restrict__ aux0, const float* __restrict__ aux1,
           const float* __restrict__ eaux0, const float* __restrict__ eaux1,
           const float* __restrict__ hin,
           int M, int Nc, int K, int acc, size_t sA, size_t sB, size_t sC)
{
  const int z = blockIdx.z;
  A += (size_t)z*sA; C += (size_t)z*sC;
  const float* Bz = B0 + (size_t)z*sB;
  __shared__ __align__(16) float As[16][68];
  __shared__ __align__(16) float Bs[16][68];
  const int tid=threadIdx.x;
  const int br=blockIdx.y*64, bc=blockIdx.x*64;
  const int rm=(tid>>4)<<2, cn=(tid&15)<<2;
  float c16[4][4]={};
  for(int k0=0;k0<K;k0+=16){
    #pragma unroll
    for(int p=0;p<4;p++){
      int idx=p*256+tid; int r=idx>>4,c=idx&15;
      int gr=br+r, gc=k0+c;
      float v=0.f;
      if(gr<M&&gc<K){
        if(AMOD==0)      v=A[(size_t)gr*K+gc];
        else if(AMOD==1) v=siluf(A[(size_t)gr*K+gc]);
        else if(AMOD==2) v=siluf((gc<128?aux0:aux1)[(size_t)gr*128+(gc&127)]);
        else if(AMOD==3) v=A[(size_t)gr*K+gc]*silugf(aux0[(size_t)gr*K+gc]);
        else if(AMOD==4) v=silugf(A[(size_t)gr*K+gc])*aux0[gc];
        else             v=A[(size_t)gr*K+gc]*aux0[gr];
      }
      As[c][r]=v;
    }
    #pragma unroll
    for(int p=0;p<4;p++){
      int idx=p*256+tid;
      float v=0.f;
      if(SEL==1){
        int kk=idx>>6, n=idx&63;
        int gk=k0+kk, gn=bc+n;
        const float* Bp=(bc<256)?B0:(bc<512)?B1:B2;
        if(gk<K&&gn<Nc) v=Bp[(size_t)gk*256+(gn&255)];
        Bs[kk][n]=v;
      } else if(SEL==2){
        int n=idx>>4, c=idx&15;
        int gn=bc+n, gk=k0+c;
        const float* Bp=(k0<256)?B0:(k0<512)?B1:B2;
        if(gn<Nc&&gk<K) v=Bp[(size_t)gn*256+(gk&255)];
        Bs[c][n]=v;
      } else if(TRB==0){
        int kk=idx>>6, n=idx&63;
        int gk=k0+kk, gn=bc+n;
        if(gk<K&&gn<Nc) v=Bz[(size_t)gk*Nc+gn];
        Bs[kk][n]=v;
      } else {
        int n=idx>>4, c=idx&15;
        int gn=bc+n, gk=k0+c;
        if(gn<Nc&&gk<K) v=Bz[(size_t)gn*K+gk];
        Bs[c][n]=v;
      }
    }
    __syncthreads();
    #pragma unroll
    for(int kk=0;kk<16;kk++){
      float4 av=*reinterpret_cast<const float4*>(&As[kk][rm]);
      float4 bv=*reinterpret_cast<const float4*>(&Bs[kk][cn]);
      float a4v[4]={av.x,av.y,av.z,av.w}, b4v[4]={bv.x,bv.y,bv.z,bv.w};
      #pragma unroll
      for(int i=0;i<4;i++)
        #pragma unroll
        for(int j=0;j<4;j++) c16[i][j]+=a4v[i]*b4v[j];
    }
    __syncthreads();
  }
  #pragma unroll
  for(int i=0;i<4;i++){
    int r=br+rm+i; if(r>=M) continue;
    #pragma unroll
    for(int j=0;j<4;j++){
      int col=bc+cn+j; if(col>=Nc) continue;
      size_t o=(size_t)r*Nc+col;
      float v=c16[i][j];
      if(EPI==0){
        float bb=bias?bias[col]:0.f;
        C[o]=(acc?C[o]:0.f)+v+bb;
      } else if(EPI==1){
        float pre=v+(bias?bias[col]:0.f);
        C[o]=pre;
        out2[o]=hin[o]+siluf(pre);
      } else if(EPI==2){
        C[o]=v*silugf(eaux0[o]);
      } else {
        size_t oo=(size_t)r*128+(col&127);
        if(col<128) C[oo]=v*silugf(eaux0[oo]);
        else        out2[oo]=v*silugf(eaux1[oo]);
      }
    }
  }
}

// ------------- 128x128-tile, 8x8 micro-tile, z-batched, for TN-row GEMMs ---
// TRB=0: C[z] = A @ B[z]   (A [M,K] shared, B [K,Nc])
// TRB=1: C[z] = A[z] @ B[z]^T  (B [Nc,K])
template<int TRB>
__global__ __launch_bounds__(256)
void gemmT(const float* __restrict__ A, const float* __restrict__ B,
           float* __restrict__ C, int M, int Nc, int K,
           size_t sA, size_t sB, size_t sC)
{
  const int z=blockIdx.z;
  A += (size_t)z*sA; C += (size_t)z*sC;
  const float* Bz = B + (size_t)z*sB;
  __shared__ __align__(16) float As[16][136];
  __shared__ __align__(16) float Bs[16][136];
  const int tid=threadIdx.x;
  const int br=blockIdx.y*128, bc=blockIdx.x*128;
  const int rm=(tid>>4)<<3, cn=(tid&15)<<3;
  float acc[8][8]={};
  for(int k0=0;k0<K;k0+=16){
    #pragma unroll
    for(int p=0;p<8;p++){
      int idx=p*256+tid; int r=idx>>4, c=idx&15;
      int gr=br+r, gc=k0+c;
      As[c][r]=(gr<M&&gc<K)? A[(size_t)gr*K+gc] : 0.f;
    }
    #pragma unroll
    for(int p=0;p<8;p++){
      int idx=p*256+tid;
      float v=0.f;
      if(TRB==0){
        int kk=idx>>7, n=idx&127;
        int gk=k0+kk, gn=bc+n;
        if(gk<K&&gn<Nc) v=Bz[(size_t)gk*Nc+gn];
        Bs[kk][n]=v;
      } else {
        int n=idx>>4, c=idx&15;
        int gn=bc+n, gk=k0+c;
        if(gn<Nc&&gk<K) v=Bz[(size_t)gn*K+gk];
        Bs[c][n]=v;
      }
    }
    __syncthreads();
    #pragma unroll
    for(int kk=0;kk<16;kk++){
      float4 a0=*reinterpret_cast<const float4*>(&As[kk][rm]);
      float4 a1=*reinterpret_cast<const float4*>(&As[kk][rm+4]);
      float4 b0=*reinterpret_cast<const float4*>(&Bs[kk][cn]);
      float4 b1=*reinterpret_cast<const float4*>(&Bs[kk][cn+4]);
      float a8[8]={a0.x,a0.y,a0.z,a0.w,a1.x,a1.y,a1.z,a1.w};
      float b8[8]={b0.x,b0.y,b0.z,b0.w,b1.x,b1.y,b1.z,b1.w};
      #pragma unroll
      for(int i=0;i<8;i++)
        #pragma unroll
        for(int j=0;j<8;j++) acc[i][j]+=a8[i]*b8[j];
    }
    __syncthreads();
  }
  // for our shapes Nc%8==0, so each 8-col block is fully in or fully out
  if(bc+cn<Nc){
    #pragma unroll
    for(int i=0;i<8;i++){
      int r=br+rm+i; if(r>=M) continue;
      float4 o0=make_float4(acc[i][0],acc[i][1],acc[i][2],acc[i][3]);
      float4 o1=make_float4(acc[i][4],acc[i][5],acc[i][6],acc[i][7]);
      *reinterpret_cast<float4*>(&C[(size_t)r*Nc+bc+cn])  =o0;
      *reinterpret_cast<float4*>(&C[(size_t)r*Nc+bc+cn+4])=o1;
    }
  }
}

// ---------------- init ----------------
__global__ void k_init(float* __restrict__ out, float* __restrict__ gpos)
{
  int i=blockIdx.x*256+threadIdx.x;
  if(i<GN) out[i]=0.f;
  if(i<NN*3) gpos[i]=0.f;
}

// ---------------- forward geometry / elementwise ----------------
__global__ void k_edge_geom(const float* __restrict__ pos, const int* __restrict__ ei,
                            float* __restrict__ dv, float* __restrict__ env,
                            float* __restrict__ denv, float* __restrict__ nrbf)
{
  int e = blockIdx.x*256+threadIdx.x; if(e>=EN) return;
  int s = ei[e], t = ei[EN+e];
  float dx=pos[3*s]-pos[3*t], dy=pos[3*s+1]-pos[3*t+1], dz=pos[3*s+2]-pos[3*t+2];
  float d = sqrtf(dx*dx+dy*dy+dz*dz);
  float u = d/CUTF, ev=0.f, dev=0.f;
  if (u<1.f){
    float u2=u*u, u4=u2*u2, u5=u4*u;
    ev  = 1.f - 21.f*u5 + 35.f*u5*u - 15.f*u5*u2;
    dev = (-105.f*u4 + 210.f*u5 - 105.f*u4*u2)/CUTF;
  }
  dv[e]=d; env[e]=ev; denv[e]=dev;
  const float C0 = sqrtf(2.f/CUTF);
  #pragma unroll
  for (int n=0;n<RBFD;n++){
    float wv = (n+1)*PIF/CUTF;
    nrbf[e*RBFD+n] = C0*sinf(wv*d)/d*ev;
  }
}

__global__ void k_ang(const float* __restrict__ pos, const int* __restrict__ ai,
                      const int* __restrict__ aj, const int* __restrict__ ak,
                      float* __restrict__ ang)
{
  int t = blockIdx.x*256+threadIdx.x; if(t>=TN) return;
  int i=ai[t], j=aj[t], k=ak[t];
  float jix=pos[3*i]-pos[3*j], jiy=pos[3*i+1]-pos[3*j+1], jiz=pos[3*i+2]-pos[3*j+2];
  float jkx=pos[3*k]-pos[3*j], jky=pos[3*k+1]-pos[3*j+1], jkz=pos[3*k+2]-pos[3*j+2];
  float cx=jiy*jkz-jiz*jky, cy=jiz*jkx-jix*jkz, cz=jix*jky-jiy*jkx;
  float cn=sqrtf(cx*cx+cy*cy+cz*cz);
  float dt=jix*jkx+jiy*jky+jiz*jkz;
  ang[t]=atan2f(cn,dt);
}

__global__ void k_sbf(const float* __restrict__ ang, const float* __restrict__ nrbf,
                      const int* __restrict__ neo0, float* __restrict__ sbf)
{
  int i = blockIdx.x*256+threadIdx.x; if(i>=TN*SBFW) return;
  int t = i/SBFW, col = i - t*SBFW;
  int l = col>>4, n = col&15;
  int e2 = neo0[t];
  sbf[i] = cosf((float)l*ang[t])*nrbf[e2*RBFD+n];
}

__global__ void k_embx(const int* __restrict__ x, const float* __restrict__ tab,
                       float* __restrict__ embx)
{
  int i = blockIdx.x*256+threadIdx.x; if(i>=NN*EMBD) return;
  int n=i>>7, c=i&127;
  embx[i]=tab[x[n]*EMBD+c];
}

// -------- attention: 4 lanes per (dst-edge, head), flash-style one pass ----
// qkv packed [E, 768] = q|k|v
__global__ void k_attn_fwd(const float* __restrict__ qkv, const float* __restrict__ esb,
                           const float* __restrict__ eatn, const int* __restrict__ neo0,
                           float* __restrict__ attn, float* __restrict__ agg)
{
  int gid = blockIdx.x*256+threadIdx.x;
  if (gid>=EN*HEADS*4) return;
  int qi = gid>>2, sub = gid&3;
  int e = qi>>4, h = qi&15;
  int n = e>>3;
  int off = h*16 + sub*4;
  float4 qv = *reinterpret_cast<const float4*>(qkv+(size_t)e*768+off);
  float4 ev = *reinterpret_cast<const float4*>(eatn+(size_t)n*CHD+off);
  float sv[7];
  float m=-1e30f, den=0.f;
  float4 av=make_float4(0.f,0.f,0.f,0.f);
  for (int jj=0;jj<7;jj++){
    int t=e*7+jj; int sE=neo0[t];
    float4 ee=*reinterpret_cast<const float4*>(esb+(size_t)t*CHD+off);
    float4 kk=*reinterpret_cast<const float4*>(qkv+(size_t)sE*768+256+off);
    float4 vv=*reinterpret_cast<const float4*>(qkv+(size_t)sE*768+512+off);
    float s = d4(qv, a4(m4(kk,ee),ev));
    s += __shfl_xor(s,1,4);
    s += __shfl_xor(s,2,4);
    s *= INVS;
    sv[jj]=s;
    float mn=fmaxf(m,s);
    float c=expf(m-mn), p=expf(s-mn);
    den = den*c + p;
    av = a4(s4(av,c), s4(m4(vv,ee),p));
    m = mn;
  }
  float rd=1.f/(den+1e-16f);
  if(sub==0){
    #pragma unroll
    for(int jj=0;jj<7;jj++)
      attn[(size_t)(e*7+jj)*HEADS+h]=expf(sv[jj]-m)*rd;
  }
  *reinterpret_cast<float4*>(agg+(size_t)e*CHD+off)=s4(av,rd);
}

__global__ void k_edge_out(const float* __restrict__ g1pre, const float* __restrict__ w2,
                           const float* __restrict__ b2, const int* __restrict__ eb,
                           float* __restrict__ ob)
{
  int e=blockIdx.x*256+threadIdx.x; if(e>=EN) return;
  float s=b2[0];
  for(int c=0;c<EMBD;c++) s += siluf(g1pre[e*EMBD+c])*w2[c];
  atomicAdd(&ob[eb[e]], s);
}

// ---------------- backward attention (4 lanes per (e,h)) ----------------
__global__ void k_attn_bwd_edge(const float* __restrict__ qkv, const float* __restrict__ esb,
                                const float* __restrict__ eatn, const float* __restrict__ attn,
                                const float* __restrict__ gagg, const int* __restrict__ neo0,
                                float* __restrict__ gqkv, float* __restrict__ gesb,
                                float* __restrict__ glog)
{
  int gid=blockIdx.x*256+threadIdx.x;
  if(gid>=EN*HEADS*4) return;
  int qi=gid>>2, sub=gid&3;
  int e=qi>>4, h=qi&15;
  int n=e>>3;
  int off=h*16+sub*4;
  float4 qv=*reinterpret_cast<const float4*>(qkv+(size_t)e*768+off);
  float4 ev=*reinterpret_cast<const float4*>(eatn+(size_t)n*CHD+off);
  float4 gv=*reinterpret_cast<const float4*>(gagg+(size_t)e*CHD+off);
  float ga[7], at[7]; int src[7];
  float sm=0.f;
  for(int jj=0;jj<7;jj++){
    int t=e*7+jj; int sE=neo0[t]; src[jj]=sE;
    at[jj]=attn[(size_t)t*HEADS+h];
    float4 ee=*reinterpret_cast<const float4*>(esb+(size_t)t*CHD+off);
    float4 vv=*reinterpret_cast<const float4*>(qkv+(size_t)sE*768+512+off);
    float s=d4(gv,m4(vv,ee));
    s += __shfl_xor(s,1,4);
    s += __shfl_xor(s,2,4);
    ga[jj]=s;
    sm += at[jj]*s;
  }
  float4 gq=make_float4(0.f,0.f,0.f,0.f);
  for(int jj=0;jj<7;jj++){
    int t=e*7+jj; int sE=src[jj];
    float gl=at[jj]*(ga[jj]-sm);
    if(sub==0) glog[(size_t)t*HEADS+h]=gl;
    float gi=gl*INVS;
    float4 ee=*reinterpret_cast<const float4*>(esb+(size_t)t*CHD+off);
    float4 kk=*reinterpret_cast<const float4*>(qkv+(size_t)sE*768+256+off);
    float4 vv=*reinterpret_cast<const float4*>(qkv+(size_t)sE*768+512+off);
    gq = fma4(gq, gi, a4(m4(kk,ee),ev));
    float4 wv = a4(s4(m4(vv,gv),at[jj]), s4(m4(qv,kk),gi));
    *reinterpret_cast<float4*>(gesb+(size_t)t*CHD+off)=wv;
  }
  *reinterpret_cast<float4*>(gqkv+(size_t)e*768+off)=gq;
}

// per src edge: its 7 triplets are t = n*56 + a*7 + (b - (b>a)), a != b
__global__ void k_attn_bwd_src(const float* __restrict__ qkv, const float* __restrict__ esb,
                               const float* __restrict__ attn, const float* __restrict__ gagg,
                               const float* __restrict__ glog, float* __restrict__ gqkv)
{
  int gid=blockIdx.x*256+threadIdx.x;
  if(gid>=EN*HEADS*4) return;
  int qi=gid>>2, sub=gid&3;
  int e=qi>>4, h=qi&15;   // e = src edge
  int n=e>>3, b=e&7;
  int off=h*16+sub*4;
  float4 gk=make_float4(0.f,0.f,0.f,0.f);
  float4 gvv=make_float4(0.f,0.f,0.f,0.f);
  for(int a=0;a<8;a++){
    if(a==b) continue;
    int t = n*56 + a*7 + (b>a ? b-1 : b);
    int de = n*8 + a;
    float gl=glog[(size_t)t*HEADS+h]*INVS;
    float at=attn[(size_t)t*HEADS+h];
    float4 ee=*reinterpret_cast<const float4*>(esb+(size_t)t*CHD+off);
    float4 qq=*reinterpret_cast<const float4*>(qkv+(size_t)de*768+off);
    float4 gg=*reinterpret_cast<const float4*>(gagg+(size_t)de*CHD+off);
    gk  = fma4(gk, gl, m4(qq,ee));
    gvv = fma4(gvv, at, m4(ee,gg));
  }
  *reinterpret_cast<float4*>(gqkv+(size_t)e*768+256+off)=gk;
  *reinterpret_cast<float4*>(gqkv+(size_t)e*768+512+off)=gvv;
}

// ---------------- backward tail ----------------
__global__ void k_edge_bwd(const float* __restrict__ geaenv, const float* __restrict__ ea,
                           const float* __restrict__ env, const float* __restrict__ denv,
                           const float* __restrict__ dv, const float* __restrict__ gnr,
                           float* __restrict__ eag, float* __restrict__ gd)
{
  int e=blockIdx.x*256+threadIdx.x; if(e>=EN) return;
  float ev=env[e], dev=denv[e], d=dv[e];
  float gmat=0.f;
  for(int m=0;m<MATD;m++){
    float g=geaenv[e*MATD+m];
    eag[e*MATD+m]=g*ev;
    gmat+=g*ea[e*MATD+m];
  }
  float acc=gmat*dev;
  const float C0=sqrtf(2.f/CUTF);
  for(int n=0;n<RBFD;n++){
    float wv=(n+1)*PIF/CUTF;
    float sn,cs; sincosf(wv*d,&sn,&cs);
    float rb=C0*sn/d;
    float rbp=C0*(wv*cs/d - sn/(d*d));
    acc += gnr[e*RBFD+n]*(rbp*ev+rb*dev);
  }
  gd[e]=acc;
}

__global__ void k_sbf_bwd(const float* __restrict__ gsbfp, const float* __restrict__ ang,
                          const float* __restrict__ dv, const float* __restrict__ env,
                          const float* __restrict__ denv, const float* __restrict__ nrbf,
                          const int* __restrict__ neo0, const int* __restrict__ ai,
                          const int* __restrict__ aj, const int* __restrict__ ak,
                          const float* __restrict__ pos,
                          float* __restrict__ gd, float* __restrict__ gpos)
{
  int t=blockIdx.x*256+threadIdx.x; if(t>=TN) return;
  const size_t PL=(size_t)TN*SBFW;
  int e2=neo0[t];
  float a=ang[t];
  float rad[16], gr[16];
  #pragma unroll
  for(int n=0;n<16;n++){ rad[n]=nrbf[e2*RBFD+n]; gr[n]=0.f; }
  float gang=0.f;
  for(int l=0;l<7;l++){
    float sl,cl; sincosf((float)l*a,&sl,&cl);
    size_t base=(size_t)t*SBFW+l*16;
    float gsum[16];
    #pragma unroll
    for(int n4=0;n4<4;n4++){
      float4 a0=*reinterpret_cast<const float4*>(gsbfp+base+n4*4);
      float4 a1=*reinterpret_cast<const float4*>(gsbfp+PL+base+n4*4);
      float4 a2=*reinterpret_cast<const float4*>(gsbfp+2*PL+base+n4*4);
      float4 a3=*reinterpret_cast<const float4*>(gsbfp+3*PL+base+n4*4);
      gsum[n4*4+0]=a0.x+a1.x+a2.x+a3.x;
      gsum[n4*4+1]=a0.y+a1.y+a2.y+a3.y;
      gsum[n4*4+2]=a0.z+a1.z+a2.z+a3.z;
      gsum[n4*4+3]=a0.w+a1.w+a2.w+a3.w;
    }
    float srow=0.f;
    #pragma unroll
    for(int n=0;n<16;n++){
      float gs=gsum[n];
      gr[n]+=gs*cl;
      srow+=gs*rad[n];
    }
    gang+=-(float)l*sl*srow;
  }
  float d2=dv[e2], ev=env[e2], dev=denv[e2];
  const float C0=sqrtf(2.f/CUTF);
  float gdd=0.f;
  for(int n=0;n<16;n++){
    float wv=(n+1)*PIF/CUTF;
    float sn,cs; sincosf(wv*d2,&sn,&cs);
    float rb=C0*sn/d2;
    float rbp=C0*(wv*cs/d2 - sn/(d2*d2));
    gdd+=gr[n]*(rbp*ev+rb*dev);
  }
  atomicAdd(&gd[e2],gdd);
  int i=ai[t], j=aj[t], k=ak[t];
  float jix=pos[3*i]-pos[3*j], jiy=pos[3*i+1]-pos[3*j+1], jiz=pos[3*i+2]-pos[3*j+2];
  float jkx=pos[3*k]-pos[3*j], jky=pos[3*k+1]-pos[3*j+1], jkz=pos[3*k+2]-pos[3*j+2];
  float cx=jiy*jkz-jiz*jky, cy=jiz*jkx-jix*jkz, cz=jix*jky-jiy*jkx;
  float cn2=cx*cx+cy*cy+cz*cz;
  float cn=sqrtf(cn2);
  float dt=jix*jkx+jiy*jky+jiz*jkz;
  float den=cn2+dt*dt;
  float coef=gang/den;
  float rc=dt/cn;
  float axv=jky*cz-jkz*cy, ayv=jkz*cx-jkx*cz, azv=jkx*cy-jky*cx;  // jk x c
  float bxv=cy*jiz-cz*jiy, byv=cz*jix-cx*jiz, bzv=cx*jiy-cy*jix;  // c x ji
  float gjix=coef*(rc*axv-cn*jkx), gjiy=coef*(rc*ayv-cn*jky), gjiz=coef*(rc*azv-cn*jkz);
  float gjkx=coef*(rc*bxv-cn*jix), gjky=coef*(rc*byv-cn*jiy), gjkz=coef*(rc*bzv-cn*jiz);
  atomicAdd(&gpos[3*i],gjix); atomicAdd(&gpos[3*i+1],gjiy); atomicAdd(&gpos[3*i+2],gjiz);
  atomicAdd(&gpos[3*k],gjkx); atomicAdd(&gpos[3*k+1],gjky); atomicAdd(&gpos[3*k+2],gjkz);
  atomicAdd(&gpos[3*j],-(gjix+gjkx)); atomicAdd(&gpos[3*j+1],-(gjiy+gjky)); atomicAdd(&gpos[3*j+2],-(gjiz+gjkz));
}

__global__ void k_d_bwd(const float* __restrict__ gd, const float* __restrict__ dv,
                        const float* __restrict__ pos, const int* __restrict__ ei,
                        float* __restrict__ gpos)
{
  int e=blockIdx.x*256+threadIdx.x; if(e>=EN) return;
  int s=ei[e], t=ei[EN+e];
  float g=gd[e]/dv[e];
  float dx=pos[3*s]-pos[3*t], dy=pos[3*s+1]-pos[3*t+1], dz=pos[3*s+2]-pos[3*t+2];
  atomicAdd(&gpos[3*s], g*dx); atomicAdd(&gpos[3*s+1], g*dy); atomicAdd(&gpos[3*s+2], g*dz);
  atomicAdd(&gpos[3*t], -g*dx); atomicAdd(&gpos[3*t+1], -g*dy); atomicAdd(&gpos[3*t+2], -g*dz);
}

// contrib[e,a,c] = sum_m G[e,a,c,m]*eag[e,m], summed over 192 edges/graph.
__global__ __launch_bounds__(256)
void k_einsum2(const float* __restrict__ G_, const float* __restrict__ eag,
               float* __restrict__ gpos)
{
  __shared__ float eL[48*MATD];
  int bid = blockIdx.x;                   // 32*18*4 = 2304
  int g = bid/72, rem = bid%72;
  int acg = rem>>2, ech = rem&3;
  int e0 = g*192 + ech*48;
  for (int i=threadIdx.x; i<48*MATD; i+=256)
    eL[i] = eag[(size_t)e0*MATD + i];
  __syncthreads();
  int wv = threadIdx.x>>6, lane = threadIdx.x&63;
  int ac = acg*4 + wv;
  float s=0.f;
  for (int e=0;e<48;e++){
    const float* Gp = G_ + ((size_t)(e0+e)*(AN*3) + ac)*MATD;
    const float* Ep = eL + e*MATD;
    s += Gp[lane]*Ep[lane];
    s += Gp[lane+64]*Ep[lane+64];
    if (lane<41) s += Gp[lane+128]*Ep[lane+128];
  }
  #pragma unroll
  for (int o=32;o>0;o>>=1) s += __shfl_down(s,o,64);
  if (lane==0) atomicAdd(&gpos[g*(AN*3)+ac], s);
}

__global__ void k_force(const float* __restrict__ gpos, float* __restrict__ ob)
{
  int i=blockIdx.x*256+threadIdx.x; if(i>=NN*3) return;
  ob[GN+i]=-gpos[i];
}

extern "C" void kernel_launch(void* const* d_in, const int* in_sizes, int n_in,
                              void* d_out, int out_size, void* d_ws, size_t ws_size,
                              hipStream_t stream)
{
  const int*   x      = (const int*)d_in[0];
  const int*   ei     = (const int*)d_in[1];
  const int*   neo    = (const int*)d_in[2];
  const int*   ai     = (const int*)d_in[3];
  const int*   aj     = (const int*)d_in[4];
  const int*   ak     = (const int*)d_in[5];
  const int*   eb     = (const int*)d_in[6];
  const float* pos    = (const float*)d_in[8];
  const float* eattr  = (const float*)d_in[9];
  const float* eagrad = (const float*)d_in[10];
  const float* etab   = (const float*)d_in[11];
  const float* matW   = (const float*)d_in[12];
  const float* matB   = (const float*)d_in[13];
  const float* rbfW   = (const float*)d_in[14];
  const float* rbfB   = (const float*)d_in[15];
  const float* embtW  = (const float*)d_in[16];
  const float* embtB  = (const float*)d_in[17];
  const float* inW    = (const float*)d_in[18];
  const float* inB    = (const float*)d_in[19];
  const float* Wq     = (const float*)d_in[20];
  const float* Wk     = (const float*)d_in[21];
  const float* Wv     = (const float*)d_in[22];
  const float* Wo     = (const float*)d_in[23];
  const float* bo     = (const float*)d_in[24];
  const float* Wsbf   = (const float*)d_in[25];
  const float* Weat   = (const float*)d_in[26];
  const float* o1W    = (const float*)d_in[27];
  const float* o1B    = (const float*)d_in[28];
  const float* o2W    = (const float*)d_in[29];
  const float* o2B    = (const float*)d_in[30];
  float* out = (float*)d_out;
  (void)in_sizes; (void)n_in; (void)out_size; (void)ws_size;

  float* w=(float*)d_ws;
  size_t off=0;
  auto A=[&](size_t n){ float* p=w+off; off+=n; return p; };
  float* dv    = A(EN);
  float* env   = A(EN);
  float* denv  = A(EN);
  float* gd    = A(EN);
  float* nrbf  = A((size_t)EN*RBFD);
  float* gnr   = A((size_t)EN*RBFD);
  float* geaenv= A((size_t)EN*MATD);
  float* eag   = A((size_t)EN*MATD);
  float* p1    = A((size_t)EN*EMBD);
  float* p2    = A((size_t)EN*EMBD);
  float* p3    = A((size_t)EN*EMBD);
  float* g1pre = A((size_t)EN*EMBD);
  float* ghpre = A((size_t)EN*EMBD);
  float* gp1   = A((size_t)EN*EMBD);
  float* gp2   = A((size_t)EN*EMBD);
  float* hlay  = A((size_t)5*EN*CHD);
  float* qkv4  = A((size_t)4*EN*768);
  float* gqkv  = A((size_t)EN*768);
  float* eatn4 = A((size_t)4*NN*CHD);
  float* sc2   = A((size_t)EN*CHD);     // agg fwd / grad_agg bwd
  float* gradh = A((size_t)EN*CHD);
  float* opre4 = A((size_t)4*EN*CHD);
  float* sbf   = A((size_t)TN*SBFW);
  float* gsbfp = A((size_t)4*TN*SBFW);  // 4 k-chunk planes, summed in k_sbf_bwd
  float* angb  = A(TN);
  float* attn4 = A((size_t)4*TN*HEADS);
  float* glog  = A((size_t)TN*HEADS);
  float* esb4  = A((size_t)4*TN*CHD);   // per-layer, stored fwd->bwd
  float* gesb4 = A((size_t)4*TN*CHD);   // per-layer, consumed by gemmT<1>
  float* embx  = A((size_t)NN*EMBD);
  float* gpos  = A((size_t)NN*3);
  // total ~160M floats ~= 640 MB

  #define GX(TRB,SEL,AMOD,EPI, Ap,B0p,B1p,B2p,biasp,Cp,o2p,a0p,a1p,e0p,e1p,hinp, M,Nc,K,acc,sA,sB,sC,batch) \
    hipLaunchKernelGGL((gemmX<TRB,SEL,AMOD,EPI>), dim3(((Nc)+63)/64,((M)+63)/64,(batch)), dim3(256),0,stream, \
      Ap,B0p,B1p,B2p,biasp,Cp,o2p,a0p,a1p,e0p,e1p,hinp, M,Nc,K,acc,(size_t)(sA),(size_t)(sB),(size_t)(sC))

  const float* FN = nullptr; float* FNm = nullptr;

  // ---------- init + geometry ----------
  hipLaunchKernelGGL(k_init, dim3((NN*3+255)/256),dim3(256),0,stream, out,gpos);
  hipLaunchKernelGGL(k_edge_geom, dim3((EN+255)/256),dim3(256),0,stream, pos,ei,dv,env,denv,nrbf);
  hipLaunchKernelGGL(k_ang, dim3((TN+255)/256),dim3(256),0,stream, pos,ai,aj,ak,angb);
  hipLaunchKernelGGL(k_sbf, dim3((TN*SBFW+255)/256),dim3(256),0,stream, angb,nrbf,neo,sbf);
  hipLaunchKernelGGL(k_embx, dim3((NN*EMBD+255)/256),dim3(256),0,stream, x,etab,embx);

  // ---------- embedding MLP ----------
  GX(0,0,5,0, eattr,matW,FN,FN, matB, p1, FNm, env,FN, FN,FN,FN, EN,EMBD,MATD,0, 0,0,0, 1);
  GX(0,0,0,0, nrbf, rbfW,FN,FN, rbfB, p2, FNm, FN,FN, FN,FN,FN, EN,EMBD,RBFD,0, 0,0,0, 1);
  GX(0,0,2,0, p1, embtW,FN,FN, embtB, p3, FNm, p1,p2, FN,FN,FN, EN,EMBD,CHD,0, 0,0,0, 1);
  GX(0,0,1,0, p3, inW,FN,FN, inB, hlay, FNm, FN,FN, FN,FN,FN, EN,CHD,EMBD,0, 0,0,0, 1);

  // ---------- batched per-layer precompute ----------
  GX(0,0,0,0, embx, Weat,FN,FN, FN, eatn4, FNm, FN,FN, FN,FN,FN,
     NN,CHD,EMBD,0, 0,(size_t)EMBD*CHD,(size_t)NN*CHD, LN);
  hipLaunchKernelGGL((gemmT<0>), dim3(2,336,4), dim3(256),0,stream,
     sbf, Wsbf, esb4, TN, CHD, SBFW, 0, (size_t)SBFW*CHD, (size_t)TN*CHD);

  // ---------- forward layers ----------
  for (int l=0;l<LN;l++){
    float* hl   = hlay+(size_t)l*EN*CHD;
    float* qkvl = qkv4+(size_t)l*EN*768;
    float* esbl = esb4+(size_t)l*TN*CHD;
    float* eatl = eatn4+(size_t)l*NN*CHD;
    float* attl = attn4+(size_t)l*TN*HEADS;
    float* opl  = opre4+(size_t)l*EN*CHD;
    GX(0,1,0,0, hl, Wq+(size_t)l*CHD*CHD, Wk+(size_t)l*CHD*CHD, Wv+(size_t)l*CHD*CHD,
       FN, qkvl, FNm, FN,FN, FN,FN,FN, EN,768,CHD,0, 0,0,0, 1);
    hipLaunchKernelGGL(k_attn_fwd, dim3((EN*HEADS*4+255)/256),dim3(256),0,stream,
                       qkvl,esbl,eatl,neo,attl,sc2);
    GX(0,0,0,1, sc2, Wo+(size_t)l*CHD*CHD,FN,FN, bo+(size_t)l*CHD, opl,
       hlay+(size_t)(l+1)*EN*CHD, FN,FN, FN,FN, hl, EN,CHD,CHD,0, 0,0,0, 1);
  }
  const float* h4=hlay+(size_t)4*EN*CHD;
  GX(0,0,0,0, h4, o1W,FN,FN, o1B, g1pre, FNm, FN,FN, FN,FN,FN, EN,EMBD,CHD,0, 0,0,0, 1);
  hipLaunchKernelGGL(k_edge_out, dim3((EN+255)/256),dim3(256),0,stream, g1pre,o2W,o2B,eb,out);

  // ---------- backward ----------
  GX(1,0,4,0, g1pre, o1W,FN,FN, FN, gradh, FNm, o2W,FN, FN,FN,FN, EN,CHD,EMBD,0, 0,0,0, 1);

  for (int l=LN-1;l>=0;l--){
    float* qkvl = qkv4+(size_t)l*EN*768;
    float* esbl = esb4+(size_t)l*TN*CHD;
    float* eatl = eatn4+(size_t)l*NN*CHD;
    float* attl = attn4+(size_t)l*TN*HEADS;
    float* opl  = opre4+(size_t)l*EN*CHD;
    float* gesbl= gesb4+(size_t)l*TN*CHD;
    GX(1,0,3,0, gradh, Wo+(size_t)l*CHD*CHD,FN,FN, FN, sc2, FNm, opl,FN, FN,FN,FN,
       EN,CHD,CHD,0, 0,0,0, 1);   // grad_agg
    hipLaunchKernelGGL(k_attn_bwd_edge, dim3((EN*HEADS*4+255)/256),dim3(256),0,stream,
                       qkvl,esbl,eatl,attl,sc2,neo,gqkv,gesbl,glog);
    hipLaunchKernelGGL(k_attn_bwd_src, dim3((EN*HEADS*4+255)/256),dim3(256),0,stream,
                       qkvl,esbl,attl,sc2,glog,gqkv);
    GX(0,2,0,0, gqkv, Wq+(size_t)l*CHD*CHD, Wk+(size_t)l*CHD*CHD, Wv+(size_t)l*CHD*CHD,
       FN, gradh, FNm, FN,FN, FN,FN,FN, EN,CHD,768,1, 0,0,0, 1);
  }

  // gsbfp[z] = gesb4[z] @ Wsbf[z]^T ; planes summed inside k_sbf_bwd
  hipLaunchKernelGGL((gemmT<1>), dim3(1,336,4), dim3(256),0,stream,
     gesb4, Wsbf, gsbfp, TN, SBFW, CHD, (size_t)TN*CHD, (size_t)SBFW*CHD, (size_t)TN*SBFW);

  GX(1,0,0,2, gradh, inW,FN,FN, FN, ghpre, FNm, FN,FN, p3,FN,FN, EN,EMBD,CHD,0, 0,0,0, 1);
  GX(1,0,0,3, ghpre, embtW,FN,FN, FN, gp1, gp2, FN,FN, p1,p2,FN, EN,CHD,EMBD,0, 0,0,0, 1);
  GX(1,0,0,0, gp2, rbfW,FN,FN, FN, gnr, FNm, FN,FN, FN,FN,FN, EN,RBFD,EMBD,0, 0,0,0, 1);
  GX(1,0,0,0, gp1, matW,FN,FN, FN, geaenv, FNm, FN,FN, FN,FN,FN, EN,MATD,EMBD,0, 0,0,0, 1);
  hipLaunchKernelGGL(k_edge_bwd, dim3((EN+255)/256),dim3(256),0,stream,
                     geaenv,eattr,env,denv,dv,gnr,eag,gd);
  hipLaunchKernelGGL(k_sbf_bwd, dim3((TN+255)/256),dim3(256),0,stream,
                     gsbfp,angb,dv,env,denv,nrbf,neo,ai,aj,ak,pos,gd,gpos);
  hipLaunchKernelGGL(k_d_bwd, dim3((EN+255)/256),dim3(256),0,stream, gd,dv,pos,ei,gpos);
  hipLaunchKernelGGL(k_einsum2, dim3(2304),dim3(256),0,stream, eagrad,eag,gpos);
  hipLaunchKernelGGL(k_force, dim3((NN*3+255)/256),dim3(256),0,stream, gpos,out);
  #undef GX
}